// Round 1
// 145.724 us; speedup vs baseline: 1.0168x; 1.0168x over previous
//
#include <hip/hip_runtime.h>
#include <hip/hip_bf16.h>
#include <math.h>

#define HW 4096
#define NN 32
#define W68 68
#define SLICE (68 * 68)   // padded positions per (n,g)

typedef __attribute__((ext_vector_type(8))) short bf16x8;
typedef __attribute__((ext_vector_type(4))) float f32x4;

__device__ inline unsigned short bfbits(float a) {
    __hip_bfloat16 h = __float2bfloat16(a);
    unsigned short u;
    __builtin_memcpy(&u, &h, 2);
    return u;
}
__device__ inline unsigned packbf(float a, float b) {
    return (unsigned)bfbits(a) | ((unsigned)bfbits(b) << 16);
}
__device__ inline float bflo(unsigned u) { return __uint_as_float(u << 16); }
__device__ inline float bfhi(unsigned u) { return __uint_as_float(u & 0xffff0000u); }

__device__ inline void bilin8(uint4 A, uint4 B, uint4 C, uint4 D,
                              const float* ww, float* val) {
    const unsigned* ua = (const unsigned*)&A;
    const unsigned* ub = (const unsigned*)&B;
    const unsigned* uc = (const unsigned*)&C;
    const unsigned* ud = (const unsigned*)&D;
    #pragma unroll
    for (int j = 0; j < 4; j++) {
        val[2*j]   = ww[0]*bflo(ua[j]) + ww[1]*bflo(ub[j]) + ww[2]*bflo(uc[j]) + ww[3]*bflo(ud[j]);
        val[2*j+1] = ww[0]*bfhi(ua[j]) + ww[1]*bfhi(ub[j]) + ww[2]*bfhi(uc[j]) + ww[3]*bfhi(ud[j]);
    }
}

// ---------------------------------------------------------------------------
// Kernel T: x[n][c][pos] fp32 -> xT[n][g][(h+2)*68+(w+2)][c16] bf16 with a
// 2-cell zero halo (memset provides the zeros). Blocks 0..119 additionally
// build the B-fragment-permuted weight buffer wperm (bf16):
//   wperm[g*7680 + which*2560 + ((kp*4+q)*16+nn)*8 + j],
//   which: 0=w_dc, 1=w_off rows 0..15, 2=w_off rows 16..17,
//   k=q*8+j -> c=k&15, tap=kp*2+(k>>4); zero for tap>=9.
// ---------------------------------------------------------------------------
__global__ __launch_bounds__(256) void transpose_x(const float* __restrict__ x,
                                                   unsigned short* __restrict__ xT,
                                                   const float* __restrict__ w_off,
                                                   const float* __restrict__ w_dc,
                                                   unsigned short* __restrict__ wperm)
{
    int bx = blockIdx.x;
    int t = threadIdx.x;

    if (bx < 120) {
        int idx = bx * 256 + t;                  // < 30720
        int g = idx / 7680;
        int r3 = idx - g * 7680;
        int which = r3 / 2560;
        int r = r3 - which * 2560;
        int j = r & 7;
        int rest = r >> 3;
        int nn_ = rest & 15; rest >>= 4;
        int q_ = rest & 3, kp_ = rest >> 2;
        int k = q_ * 8 + j;
        int c = k & 15, tt = kp_ * 2 + (k >> 4);
        float v = 0.f;
        if (tt < 9) {
            if (which == 0)      v = w_dc[(g * 16 + nn_) * 144 + c * 9 + tt];
            else if (which == 1) v = w_off[(g * 18 + nn_) * 144 + c * 9 + tt];
            else if (nn_ < 2)    v = w_off[(g * 18 + 16 + nn_) * 144 + c * 9 + tt];
        }
        wperm[idx] = bfbits(v);
    }

    __shared__ float tile[256 * 17];
    int n = bx >> 6, g = (bx >> 4) & 3, chunk = bx & 15;
    const float* xb = x + (size_t)(n * 64 + g * 16) * HW + chunk * 256;

    #pragma unroll
    for (int r = 0; r < 16; r++) {
        int idx = r * 256 + t;
        int c = idx >> 8, p = idx & 255;
        tile[p * 17 + c] = xb[c * HW + p];
    }
    __syncthreads();

    unsigned short* ob = xT + (size_t)(n * 4 + g) * SLICE * 16;
    #pragma unroll
    for (int r = 0; r < 2; r++) {
        int idx = r * 256 + t;
        int p = idx >> 1, half = idx & 1;
        int pos = chunk * 256 + p;
        int h = pos >> 6, w = pos & 63;
        const float* tp = &tile[p * 17 + half * 8];
        uint4 v;
        v.x = packbf(tp[0], tp[1]);
        v.y = packbf(tp[2], tp[3]);
        v.z = packbf(tp[4], tp[5]);
        v.w = packbf(tp[6], tp[7]);
        *(uint4*)(ob + ((size_t)((h + 2) * W68 + (w + 2)) * 16 + half * 8)) = v;
    }
}

// ---------------------------------------------------------------------------
// Kernel F: fused offset-conv + deformable conv, in-register MFMA, halo'd xT.
// grid 2048 = 32n*4g*16chunk ; block 256 = 4 waves ; 64 pos/wave.
// Restructured for MLP: no wfrag staging (weights read straight from L2-hot
// wperm), depth-2 software ring over the 20 (kp,s) gather units, tap==9
// handled branch-free via zeroed off_lds pad + zero B-fragment slots.
// ---------------------------------------------------------------------------
__global__ __launch_bounds__(256, 4) void fused_conv(const unsigned short* __restrict__ xT,
                                                     const unsigned short* __restrict__ wperm,
                                                     const float* __restrict__ b_off,
                                                     const float* __restrict__ b_dc,
                                                     float* __restrict__ outpre)
{
    __shared__ __attribute__((aligned(8))) unsigned short off_lds[256 * 20];

    int bx = blockIdx.x;
    int n = bx >> 6, g = (bx >> 4) & 3, chunk = bx & 15;
    int t = threadIdx.x;
    int lane = t & 63, wv = t >> 6;
    int nn = lane & 15, q = lane >> 4;
    int t2 = q >> 1, chh = q & 1;

    const unsigned short* wpg = wperm + g * 7680;
    const unsigned short* xw = xT + (size_t)(n * 4 + g) * SLICE * 16 + chh * 8;

    // per-s position constants
    int pls[4]; float fy[4], fx[4]; int basep[4];
    #pragma unroll
    for (int s = 0; s < 4; s++) {
        int pl = (wv * 4 + s) * 16 + nn;
        int pos = chunk * 256 + pl;
        int h = pos >> 6, w = pos & 63;
        pls[s] = pl;
        fy[s] = (float)(h - 1);
        fx[s] = (float)(w - 1);
        basep[s] = (h + 1) * W68 + (w + 1);
    }

    // ================= Phase 1: offset conv =================
    {
        // B-fragments straight from global (15KB/g, shared by 512 blocks -> L2)
        bf16x8 pb0[5], pb1[5];
        #pragma unroll
        for (int kp = 0; kp < 5; kp++) {
            int fo = ((kp * 4 + q) * 16 + nn) * 8;
            pb0[kp] = *(const bf16x8*)(wpg + 2560 + fo);
            pb1[kp] = *(const bf16x8*)(wpg + 5120 + fo);
        }

        f32x4 acc0[4], acc1[4];
        float bv0 = b_off[g * 18 + nn];
        float bv1 = (nn < 2) ? b_off[g * 18 + 16 + nn] : 0.f;
        #pragma unroll
        for (int s = 0; s < 4; s++)
            #pragma unroll
            for (int r = 0; r < 4; r++) { acc0[s][r] = bv0; acc1[s][r] = bv1; }

        uint4 xv[2][4];
        // depth-2 ring over kp: stage kp+1's loads while kp's MFMAs run
        auto stage1 = [&](int kp) {
            int ki = t2 ? (2 * kp + 1) / 3 : (2 * kp) / 3;
            int kj = t2 ? (2 * kp + 1) % 3 : (2 * kp) % 3;
            int xo = ki * W68 + kj;
            int sl = kp & 1;
            #pragma unroll
            for (int s = 0; s < 4; s++)
                xv[sl][s] = *(const uint4*)(xw + (size_t)(basep[s] + xo) * 16);
        };
        stage1(0);
        #pragma unroll
        for (int kp = 0; kp < 5; kp++) {
            if (kp < 4) stage1(kp + 1);
            int sl = kp & 1;
            #pragma unroll
            for (int s = 0; s < 4; s++) {
                bf16x8 af = *(bf16x8*)&xv[sl][s];
                acc0[s] = __builtin_amdgcn_mfma_f32_16x16x32_bf16(af, pb0[kp], acc0[s], 0, 0, 0);
                acc1[s] = __builtin_amdgcn_mfma_f32_16x16x32_bf16(af, pb1[kp], acc1[s], 0, 0, 0);
            }
        }

        #pragma unroll
        for (int s = 0; s < 4; s++) {
            int pl = (wv * 4 + s) * 16 + q * 4;
            #pragma unroll
            for (int r = 0; r < 4; r++) {
                off_lds[(pl + r) * 20 + nn] = bfbits(acc0[s][r]);
                if (nn < 2)
                    off_lds[(pl + r) * 20 + 16 + nn] = bfbits(acc1[s][r]);
            }
        }
        // zero the 2-short row pad: tap==9 then reads dy=dx=0 (safe clamped
        // addresses) and its B-fragment slots in wperm are zero -> exact 0
        // contribution, no divergent branch needed in phase 2.
        off_lds[t * 20 + 18] = 0;
        off_lds[t * 20 + 19] = 0;
    }

    // phase-2 B-fragments: issue before the barrier so latency hides under it
    bf16x8 bwr[5];
    #pragma unroll
    for (int kp = 0; kp < 5; kp++)
        bwr[kp] = *(const bf16x8*)(wpg + ((kp * 4 + q) * 16 + nn) * 8);

    __syncthreads();

    // ================= Phase 2: deformable conv =================
    f32x4 acc[4];
    float bv = b_dc[g * 16 + nn];
    #pragma unroll
    for (int s = 0; s < 4; s++)
        #pragma unroll
        for (int r = 0; r < 4; r++) acc[s][r] = bv;

    uint4 RA[2], RB[2], RC[2], RD[2];
    float rw[2][4];

    // stage(u): off -> bilinear weights + 4 gathers into ring slot u&1
    auto stage = [&](int u) {
        int kp = u >> 2, s = u & 3, sl = u & 1;
        int ki = t2 ? (2 * kp + 1) / 3 : (2 * kp) / 3;
        int kj = t2 ? (2 * kp + 1) % 3 : (2 * kp) % 3;
        int tap2 = 4 * kp + 2 * t2;   // 2*tap
        unsigned uo = *(const unsigned*)&off_lds[pls[s] * 20 + tap2];
        float py = fy[s] + (float)ki + bflo(uo);
        float px = fx[s] + (float)kj + bfhi(uo);
        float y0f = fminf(fmaxf(floorf(py), -2.f), 64.f);
        float x0f = fminf(fmaxf(floorf(px), -2.f), 64.f);
        float ly = py - y0f, lx = px - x0f;
        float my = 1.f - ly, mx = 1.f - lx;
        rw[sl][0] = my * mx; rw[sl][1] = my * lx;
        rw[sl][2] = ly * mx; rw[sl][3] = ly * lx;
        int base = (int)(y0f * 68.f + x0f) + 138;   // exact: small ints in f32
        const unsigned short* p0 = xw + (size_t)base * 16;
        RA[sl] = *(const uint4*)(p0);
        RB[sl] = *(const uint4*)(p0 + 16);
        RC[sl] = *(const uint4*)(p0 + W68 * 16);
        RD[sl] = *(const uint4*)(p0 + W68 * 16 + 16);
    };
    // consume(u): bilinear + pack + MFMA
    auto consume = [&](int u) {
        int kp = u >> 2, s = u & 3, sl = u & 1;
        float val[8];
        bilin8(RA[sl], RB[sl], RC[sl], RD[sl], rw[sl], val);
        bf16x8 af;
        #pragma unroll
        for (int j = 0; j < 8; j++) af[j] = (short)bfbits(val[j]);
        acc[s] = __builtin_amdgcn_mfma_f32_16x16x32_bf16(af, bwr[kp], acc[s], 0, 0, 0);
    };

    stage(0);
    #pragma unroll
    for (int u = 0; u < 20; u++) {
        if (u < 19) stage(u + 1);
        consume(u);
    }

    float* op = outpre + (size_t)(n * 64 + g * 16) * HW;
    #pragma unroll
    for (int s = 0; s < 4; s++) {
        int pbase = chunk * 256 + (wv * 4 + s) * 16 + q * 4;
        #pragma unroll
        for (int r = 0; r < 4; r++)
            op[nn * HW + pbase + r] = acc[s][r];
    }
}

// ---------------------------------------------------------------------------
// Kernel C: per-(n,cout) mean/var (single pass) + sigmoid-form tanh GELU.
// ---------------------------------------------------------------------------
__global__ __launch_bounds__(256) void norm_gelu(const float* __restrict__ outpre,
                                                 float* __restrict__ out)
{
    __shared__ float red[8];
    int bx = blockIdx.x;
    int n  = bx >> 6;
    int co = bx & 63;
    int t  = threadIdx.x;

    const float4* base = (const float4*)(outpre + (size_t)(n * 64 + co) * HW);
    float4 v[4];
    float s = 0.f, sq = 0.f;
    #pragma unroll
    for (int r = 0; r < 4; r++) {
        v[r] = base[t + r * 256];
        s  += v[r].x + v[r].y + v[r].z + v[r].w;
        sq  = fmaf(v[r].x, v[r].x, sq);
        sq  = fmaf(v[r].y, v[r].y, sq);
        sq  = fmaf(v[r].z, v[r].z, sq);
        sq  = fmaf(v[r].w, v[r].w, sq);
    }
    #pragma unroll
    for (int o2 = 32; o2 > 0; o2 >>= 1) {
        s  += __shfl_down(s,  o2, 64);
        sq += __shfl_down(sq, o2, 64);
    }
    int wid = t >> 6, lane = t & 63;
    if (lane == 0) { red[wid] = s; red[4 + wid] = sq; }
    __syncthreads();
    float S  = red[0] + red[1] + red[2] + red[3];
    float SQ = red[4] + red[5] + red[6] + red[7];
    float mean = S * (1.f / 4096.f);
    float var  = SQ * (1.f / 4096.f) - mean * mean;
    float rstd = rsqrtf(var + 1e-5f);

    int b = n >> 3, d = n & 7;
    float4* outp = (float4*)(out + ((size_t)(b * 64 + co) * 8 + d) * HW);
    #pragma unroll
    for (int r = 0; r < 4; r++) {
        float xs[4] = {v[r].x, v[r].y, v[r].z, v[r].w};
        float4 res;
        float* rp = (float*)&res;
        #pragma unroll
        for (int qq = 0; qq < 4; qq++) {
            float xn = (xs[qq] - mean) * rstd;
            float u = xn * (1.5957691f + 0.0713548162f * xn * xn);
            float e = __expf(-u);
            rp[qq] = xn * __frcp_rn(1.f + e);
        }
        outp[t + r * 256] = res;
    }
}

// ---------------------------------------------------------------------------
extern "C" void kernel_launch(void* const* d_in, const int* in_sizes, int n_in,
                              void* d_out, int out_size, void* d_ws, size_t ws_size,
                              hipStream_t stream) {
    const float* x     = (const float*)d_in[0];
    const float* w_off = (const float*)d_in[1];
    const float* b_off = (const float*)d_in[2];  (void)b_off;
    const float* w_dc  = (const float*)d_in[3];
    const float* b_dc  = (const float*)d_in[4];
    float* out = (float*)d_out;

    unsigned short* wperm = (unsigned short*)d_ws;                   // 61,440 B
    unsigned short* xTb   = wperm + 30720;                           // 18.94 MB
    float* outpre = (float*)(xTb + (size_t)NN * 4 * SLICE * 16);     // 33.55 MB

    // zero wperm + halo'd xT (interior overwritten by transpose_x)
    hipMemsetAsync(d_ws, 0, 61440 + (size_t)NN * 4 * SLICE * 16 * 2, stream);

    transpose_x<<<2048, 256, 0, stream>>>(x, xTb, w_off, w_dc, wperm);
    fused_conv <<<2048, 256, 0, stream>>>(xTb, wperm,
                                          (const float*)d_in[2], b_dc, outpre);
    norm_gelu  <<<2048, 256, 0, stream>>>(outpre, out);
}